// Round 2
// baseline (191.785 us; speedup 1.0000x reference)
//
#include <hip/hip_runtime.h>

#define NB 16
#define SS 2048
#define DD 64

typedef __attribute__((ext_vector_type(8))) short short8;
typedef __attribute__((ext_vector_type(4))) float f32x4;

// SCALE * log2(e), folded so softmax exp is one v_mul + one v_exp
#define SCL2E 0.18033688011112042f

// round-to-nearest-even f32 -> bf16 (as raw short)
__device__ __forceinline__ short f2bf(float f) {
  union { float f; unsigned u; } v; v.f = f;
  unsigned r = (v.u + 0x7fffu + ((v.u >> 16) & 1u)) >> 16;
  return (short)r;
}

// packed RNE f32x2 -> bf16x2 (no builtin on gfx950; guide T12)
__device__ __forceinline__ unsigned cvtpk_bf16(float lo, float hi) {
  unsigned r;
  asm("v_cvt_pk_bf16_f32 %0, %1, %2" : "=v"(r) : "v"(lo), "v"(hi));
  return r;
}

__device__ __forceinline__ short8 load_a_frag_f32(const float* p) {
  float4 u = *(const float4*)p;
  float4 w = *(const float4*)(p + 4);
  short8 r;
  r[0] = f2bf(u.x); r[1] = f2bf(u.y); r[2] = f2bf(u.z); r[3] = f2bf(u.w);
  r[4] = f2bf(w.x); r[5] = f2bf(w.y); r[6] = f2bf(w.z); r[7] = f2bf(w.w);
  return r;
}

// ---------------------------------------------------------------------------
// One-shot W transpose: Wt[m][n][k] = W[k][n] as bf16, k-contiguous.
// ---------------------------------------------------------------------------
__global__ __launch_bounds__(256) void wprep_kernel(
    const float* __restrict__ Wq, const float* __restrict__ Wk,
    const float* __restrict__ Wv, ushort* __restrict__ Wt)
{
  const float* Ws[3] = {Wq, Wk, Wv};
  const int m = blockIdx.x;
  const float* src = Ws[m];
  ushort* dst = Wt + m * 4096;
  const int t = threadIdx.x;
#pragma unroll
  for (int i = 0; i < 4; ++i) {
    int idx = i * 1024 + t * 4;
    int k = idx >> 6, n0 = idx & 63;
    float4 w4 = *(const float4*)(src + idx);
    dst[(n0 + 0) * 64 + k] = (ushort)f2bf(w4.x);
    dst[(n0 + 1) * 64 + k] = (ushort)f2bf(w4.y);
    dst[(n0 + 2) * 64 + k] = (ushort)f2bf(w4.z);
    dst[(n0 + 3) * 64 + k] = (ushort)f2bf(w4.w);
  }
}

// ---------------------------------------------------------------------------
// QKV projection v3: 32 x-rows per block, 6 waves (384 thr), one wave per
// (m, row-half) -> 3x the wave count of v2, 1/4 the serial chain per wave.
// Lane(l15,quad) holds out[row=g(l15)][col = nt*16 + quad*4 + r] -> packed
// 8B store. V goes to LDS for the vT transpose.
// ---------------------------------------------------------------------------
__global__ __launch_bounds__(384) void proj_kernel(
    const float* __restrict__ x, const ushort* __restrict__ Wt,
    const float* __restrict__ bq, const float* __restrict__ bk,
    const float* __restrict__ bv,
    ushort* __restrict__ qo, ushort* __restrict__ ko, ushort* __restrict__ vT)
{
  __shared__ __align__(16) ushort Vs[32][68];
  const int t = threadIdx.x;
  const int lane = t & 63, w = t >> 6;       // w in 0..5
  const int l15 = lane & 15, quad = lane >> 4;
  const int m = w >> 1, rh = w & 1;          // m: 0=q 1=k 2=v ; rh: row half
  const int g = blockIdx.x * 32 + rh * 16 + l15;

  // B-frags: x row g (redundant across m-waves; L1 hits)
  short8 b0 = load_a_frag_f32(x + (size_t)g * 64 + quad * 8);
  short8 b1 = load_a_frag_f32(x + (size_t)g * 64 + 32 + quad * 8);

  const float* bp = (m == 0 ? bq : (m == 1 ? bk : bv));
  const ushort* wm = Wt + m * 4096;
  ushort* outp = (m == 0 ? qo : ko);

#pragma unroll
  for (int nt = 0; nt < 4; ++nt) {
    const ushort* ap = wm + (nt * 16 + l15) * 64 + quad * 8;
    short8 a0 = *(const short8*)ap;
    short8 a1 = *(const short8*)(ap + 32);
    f32x4 acc = {0.f, 0.f, 0.f, 0.f};
    acc = __builtin_amdgcn_mfma_f32_16x16x32_bf16(a0, b0, acc, 0, 0, 0);
    acc = __builtin_amdgcn_mfma_f32_16x16x32_bf16(a1, b1, acc, 0, 0, 0);
    float4 bb = *(const float4*)(bp + nt * 16 + quad * 4);
    uint2 pk;
    pk.x = cvtpk_bf16(acc[0] + bb.x, acc[1] + bb.y);
    pk.y = cvtpk_bf16(acc[2] + bb.z, acc[3] + bb.w);
    if (m == 2) {
      *(uint2*)&Vs[rh * 16 + l15][nt * 16 + quad * 4] = pk;
    } else {
      *(uint2*)(outp + (size_t)g * 64 + nt * 16 + quad * 4) = pk;
    }
  }
  __syncthreads();
  if (t < 256) {
    const int batch = blockIdx.x >> 6;
    const int s0 = (blockIdx.x & 63) * 32;
    const int d = t >> 2, j0 = (t & 3) * 8;
    ushort tmp[8];
#pragma unroll
    for (int j = 0; j < 8; ++j) tmp[j] = Vs[j0 + j][d];
    *(int4*)(vT + (size_t)batch * DD * SS + (size_t)d * SS + s0 + j0) =
        *(const int4*)tmp;
  }
}

// ---------------------------------------------------------------------------
// In-register P redistribution (unchanged from r1; verified passing).
// ---------------------------------------------------------------------------
__device__ __forceinline__ short8 build_pa(unsigned A0, unsigned A1,
                                           unsigned B0, unsigned B1, int quad) {
  int xA0 = __shfl_xor((int)A0, 32);
  int xA1 = __shfl_xor((int)A1, 32);
  int xB0 = __shfl_xor((int)B0, 32);
  int xB1 = __shfl_xor((int)B1, 32);
  const bool hi = quad >= 2;
  const bool odd = quad & 1;
  int Lo0 = hi ? xB0 : (int)A0;   // [A_lo | B_lo]
  int Lo1 = hi ? xB1 : (int)A1;
  int Hi0 = hi ? (int)B0 : xA0;   // [A_hi | B_hi]
  int Hi1 = hi ? (int)B1 : xA1;
  int xLo0 = __shfl_xor(Lo0, 16);
  int xLo1 = __shfl_xor(Lo1, 16);
  int xHi0 = __shfl_xor(Hi0, 16);
  int xHi1 = __shfl_xor(Hi1, 16);
  int4 wv;
  wv.x = odd ? xHi0 : Lo0;   // keys quad*8 + 0,1
  wv.y = odd ? xHi1 : Lo1;   // keys quad*8 + 2,3
  wv.z = odd ? Hi0 : xLo0;   // keys quad*8 + 4,5
  wv.w = odd ? Hi1 : xLo1;   // keys quad*8 + 6,7
  return *(short8*)&wv;
}

// exp + in-register P build + PV for one 16-query tile. MASKED compile-time.
template<bool MASKED>
__device__ __forceinline__ void attn_half(
    const f32x4 (&c)[4], float& l_acc, f32x4 (&acc)[4],
    const short8 (&vf0)[4], const short8 (&vf1)[4],
    int keybase, int qabs, int quad)
{
  unsigned pk[4][2];
#pragma unroll
  for (int ct = 0; ct < 4; ++ct) {
    float pe[4];
#pragma unroll
    for (int r = 0; r < 4; ++r) {
      float p = __builtin_amdgcn_exp2f(c[ct][r] * SCL2E);
      if (MASKED && (keybase + ct * 16 + quad * 4 + r > qabs)) p = 0.f;
      pe[r] = p;
      l_acc += p;
    }
    pk[ct][0] = cvtpk_bf16(pe[0], pe[1]);
    pk[ct][1] = cvtpk_bf16(pe[2], pe[3]);
  }
  short8 pa0 = build_pa(pk[0][0], pk[0][1], pk[1][0], pk[1][1], quad);
  short8 pa1 = build_pa(pk[2][0], pk[2][1], pk[3][0], pk[3][1], quad);
  __builtin_amdgcn_s_setprio(1);
#pragma unroll
  for (int nt = 0; nt < 4; ++nt) {
    acc[nt] = __builtin_amdgcn_mfma_f32_16x16x32_bf16(pa0, vf0[nt], acc[nt], 0, 0, 0);
    acc[nt] = __builtin_amdgcn_mfma_f32_16x16x32_bf16(pa1, vf1[nt], acc[nt], 0, 0, 0);
  }
  __builtin_amdgcn_s_setprio(0);
}

// ---------------------------------------------------------------------------
// Flash causal attention v3: 16 queries/block (grid 2048 -> whole grid
// co-resident, ~6 waves/SIMD), 4 waves key-split, in-register softmax.
// ---------------------------------------------------------------------------
__global__ __launch_bounds__(256, 6) void attn_kernel(
    const ushort* __restrict__ qg, const ushort* __restrict__ kg,
    const ushort* __restrict__ vT, float* __restrict__ out)
{
  __shared__ __align__(16) float accW[4][16][68];
  __shared__ float lW[4][16];

  const int t = threadIdx.x, bid = blockIdx.x;
  const int batch = bid & 15;                // round-robins batches over XCDs
  const int qt = 127 - (bid >> 4);           // heavy q-tiles first
  const int q0 = qt * 16;
  const int lane = t & 63, w = t >> 6;
  const int l15 = lane & 15, quad = lane >> 4;
  const size_t bbase = (size_t)batch * SS * DD;

  // Q fragments (B operand of swapped QK): lane l15 = query row
  const ushort* qp = qg + bbase + (size_t)(q0 + l15) * 64 + quad * 8;
  short8 a0 = *(const short8*)qp;
  short8 a1 = *(const short8*)(qp + 32);

  f32x4 acc0[4];
  float l0 = 0.f;
#pragma unroll
  for (int nt = 0; nt < 4; ++nt) acc0[nt] = (f32x4){0.f, 0.f, 0.f, 0.f};

  const int ktotal = ((q0 + 15) >> 6) + 1;   // 64-key tiles
  const ushort* kp0 = kg + bbase + (size_t)(w * 64 + l15) * 64 + quad * 8;
  const ushort* kp1 = kp0 + 2048;            // +32 key rows
  const ushort* vp0 = vT + bbase + (size_t)(l15) * SS + w * 64 + quad * 8;
  const ushort* vp1 = vp0 + 16 * SS;
  const ushort* vp2 = vp0 + 32 * SS;
  const ushort* vp3 = vp0 + 48 * SS;

  const int qabs0 = q0 + l15;

  for (int kt = w; kt < ktotal; kt += 4) {
    short8 kf0[4], kf1[4], vf0[4], vf1[4];
    kf0[0] = *(const short8*)(kp0);
    kf1[0] = *(const short8*)(kp0 + 32);
    kf0[1] = *(const short8*)(kp0 + 1024);
    kf1[1] = *(const short8*)(kp0 + 1056);
    kf0[2] = *(const short8*)(kp1);
    kf1[2] = *(const short8*)(kp1 + 32);
    kf0[3] = *(const short8*)(kp1 + 1024);
    kf1[3] = *(const short8*)(kp1 + 1056);
    vf0[0] = *(const short8*)(vp0); vf1[0] = *(const short8*)(vp0 + 32);
    vf0[1] = *(const short8*)(vp1); vf1[1] = *(const short8*)(vp1 + 32);
    vf0[2] = *(const short8*)(vp2); vf1[2] = *(const short8*)(vp2 + 32);
    vf0[3] = *(const short8*)(vp3); vf1[3] = *(const short8*)(vp3 + 32);

    // Swapped QK: c = mfma(K, Q) -> S^T tile; lane l15 = query.
    f32x4 c0[4];
    __builtin_amdgcn_s_setprio(1);
#pragma unroll
    for (int ct = 0; ct < 4; ++ct) {
      f32x4 z = {0.f, 0.f, 0.f, 0.f};
      c0[ct] = __builtin_amdgcn_mfma_f32_16x16x32_bf16(kf0[ct], a0, z, 0, 0, 0);
      c0[ct] = __builtin_amdgcn_mfma_f32_16x16x32_bf16(kf1[ct], a1, c0[ct], 0, 0, 0);
    }
    __builtin_amdgcn_s_setprio(0);

    const int kb = kt * 64;
    if (kt == ktotal - 1) {
      attn_half<true >(c0, l0, acc0, vf0, vf1, kb, qabs0, quad);
    } else {
      attn_half<false>(c0, l0, acc0, vf0, vf1, kb, qabs0, quad);
    }
    kp0 += 16384; kp1 += 16384;
    vp0 += 256; vp1 += 256; vp2 += 256; vp3 += 256;
  }

  // l is per-lane (q = l15); sum across the 4 quads holding different keys
  l0 += __shfl_xor(l0, 16); l0 += __shfl_xor(l0, 32);

#pragma unroll
  for (int r = 0; r < 4; ++r)
#pragma unroll
    for (int nt = 0; nt < 4; ++nt)
      accW[w][quad * 4 + r][nt * 16 + l15] = acc0[nt][r];
  if (lane < 16) lW[w][lane] = l0;
  __syncthreads();

  // combine: 256 threads cover 16 rows x 64 cols, 4 floats each
  {
    const int row = t >> 4, col0 = (t & 15) * 4;
    float den = lW[0][row] + lW[1][row] + lW[2][row] + lW[3][row];
    float iv = 1.0f / den;
    float4 o = {0.f, 0.f, 0.f, 0.f};
#pragma unroll
    for (int ww = 0; ww < 4; ++ww) {
      float4 x0 = *(const float4*)&accW[ww][row][col0];
      o.x += x0.x; o.y += x0.y; o.z += x0.z; o.w += x0.w;
    }
    o.x *= iv; o.y *= iv; o.z *= iv; o.w *= iv;
    *(float4*)(out + bbase + (size_t)(q0 + row) * 64 + col0) = o;
  }
}

extern "C" void kernel_launch(void* const* d_in, const int* in_sizes, int n_in,
                              void* d_out, int out_size, void* d_ws, size_t ws_size,
                              hipStream_t stream) {
  (void)in_sizes; (void)n_in; (void)out_size; (void)ws_size;
  const float* x  = (const float*)d_in[0];
  const float* Wq = (const float*)d_in[1];
  const float* bq = (const float*)d_in[2];
  const float* Wk = (const float*)d_in[3];
  const float* bk = (const float*)d_in[4];
  const float* Wv = (const float*)d_in[5];
  const float* bv = (const float*)d_in[6];
  float* out = (float*)d_out;

  ushort* qws = (ushort*)d_ws;                       // bf16 q: 4 MB
  ushort* kws = qws + (size_t)NB * SS * DD;          // bf16 k: 4 MB
  ushort* vws = kws + (size_t)NB * SS * DD;          // bf16 v^T: 4 MB
  ushort* wt  = vws + (size_t)NB * SS * DD;          // bf16 W^T[3][64][64]: 24 KB

  wprep_kernel<<<dim3(3), dim3(256), 0, stream>>>(Wq, Wk, Wv, wt);
  proj_kernel<<<dim3(NB * SS / 32), dim3(384), 0, stream>>>(
      x, wt, bq, bk, bv, qws, kws, vws);
  attn_kernel<<<dim3(NB * (SS / 16)), dim3(256), 0, stream>>>(
      qws, kws, vws, out);
}

// Round 3
// 126.265 us; speedup vs baseline: 1.5189x; 1.5189x over previous
//
#include <hip/hip_runtime.h>

#define NB 16
#define SS 2048
#define DD 64

typedef __attribute__((ext_vector_type(8))) short short8;
typedef __attribute__((ext_vector_type(4))) float f32x4;

// SCALE * log2(e), folded so softmax exp is one v_mul + one v_exp
#define SCL2E 0.18033688011112042f

// round-to-nearest-even f32 -> bf16 (as raw short)
__device__ __forceinline__ short f2bf(float f) {
  union { float f; unsigned u; } v; v.f = f;
  unsigned r = (v.u + 0x7fffu + ((v.u >> 16) & 1u)) >> 16;
  return (short)r;
}

// packed RNE f32x2 -> bf16x2 (no builtin on gfx950; guide T12)
__device__ __forceinline__ unsigned cvtpk_bf16(float lo, float hi) {
  unsigned r;
  asm("v_cvt_pk_bf16_f32 %0, %1, %2" : "=v"(r) : "v"(lo), "v"(hi));
  return r;
}

__device__ __forceinline__ short8 load_a_frag_f32(const float* p) {
  float4 u = *(const float4*)p;
  float4 w = *(const float4*)(p + 4);
  short8 r;
  r[0] = f2bf(u.x); r[1] = f2bf(u.y); r[2] = f2bf(u.z); r[3] = f2bf(u.w);
  r[4] = f2bf(w.x); r[5] = f2bf(w.y); r[6] = f2bf(w.z); r[7] = f2bf(w.w);
  return r;
}

// ---------------------------------------------------------------------------
// QKV projection (r0 version, 31 us proven). Block = 4 waves = 64 seq rows.
// W converted bf16->LDS once per block; Q,K row-major bf16; V transposed.
// ---------------------------------------------------------------------------
__global__ __launch_bounds__(256) void proj_kernel(
    const float* __restrict__ x,
    const float* __restrict__ Wq, const float* __restrict__ bq,
    const float* __restrict__ Wk, const float* __restrict__ bk,
    const float* __restrict__ Wv, const float* __restrict__ bv,
    ushort* __restrict__ qo, ushort* __restrict__ ko, ushort* __restrict__ vT)
{
  __shared__ __align__(16) ushort Wt[3][64][72];   // W^T[n][k], bf16
  __shared__ __align__(16) ushort Vs[64][68];
  const int t = threadIdx.x;
  {
    const float* Ws[3] = {Wq, Wk, Wv};
    for (int m = 0; m < 3; ++m)
      for (int i = 0; i < 4; ++i) {
        int idx = i * 1024 + t * 4;
        int kk = idx >> 6, n0 = idx & 63;
        float4 w4 = *(const float4*)(Ws[m] + kk * 64 + n0);
        Wt[m][n0 + 0][kk] = (ushort)f2bf(w4.x);
        Wt[m][n0 + 1][kk] = (ushort)f2bf(w4.y);
        Wt[m][n0 + 2][kk] = (ushort)f2bf(w4.z);
        Wt[m][n0 + 3][kk] = (ushort)f2bf(w4.w);
      }
  }
  __syncthreads();

  const int lane = t & 63, w = t >> 6;
  const int l15 = lane & 15, quad = lane >> 4;
  const int g = blockIdx.x * 64 + w * 16 + l15;
  short8 a0 = load_a_frag_f32(x + (size_t)g * 64 + quad * 8);
  short8 a1 = load_a_frag_f32(x + (size_t)g * 64 + 32 + quad * 8);
  const int lrow0 = w * 16 + quad * 4;
  const int row0 = blockIdx.x * 64 + lrow0;

  for (int m = 0; m < 3; ++m) {
    const float* bp = (m == 0 ? bq : (m == 1 ? bk : bv));
    for (int nt = 0; nt < 4; ++nt) {
      short8 b0 = *(const short8*)&Wt[m][nt * 16 + l15][quad * 8];
      short8 b1 = *(const short8*)&Wt[m][nt * 16 + l15][32 + quad * 8];
      f32x4 acc = {0.f, 0.f, 0.f, 0.f};
      acc = __builtin_amdgcn_mfma_f32_16x16x32_bf16(a0, b0, acc, 0, 0, 0);
      acc = __builtin_amdgcn_mfma_f32_16x16x32_bf16(a1, b1, acc, 0, 0, 0);
      float bb = bp[nt * 16 + l15];
      if (m == 0) {
        for (int r = 0; r < 4; ++r)
          qo[(size_t)(row0 + r) * 64 + nt * 16 + l15] = (ushort)f2bf(acc[r] + bb);
      } else if (m == 1) {
        for (int r = 0; r < 4; ++r)
          ko[(size_t)(row0 + r) * 64 + nt * 16 + l15] = (ushort)f2bf(acc[r] + bb);
      } else {
        for (int r = 0; r < 4; ++r)
          Vs[lrow0 + r][nt * 16 + l15] = (ushort)f2bf(acc[r] + bb);
      }
    }
  }
  __syncthreads();
  {
    const int batch = blockIdx.x >> 5;
    const int s0 = (blockIdx.x & 31) * 64;
    const int d = t >> 2, j0 = (t & 3) * 16;
    ushort tmp[16];
    for (int j = 0; j < 16; ++j) tmp[j] = Vs[j0 + j][d];
    ushort* dst = vT + (size_t)batch * DD * SS + (size_t)d * SS + s0 + j0;
    ((int4*)dst)[0] = ((int4*)tmp)[0];
    ((int4*)dst)[1] = ((int4*)tmp)[1];
  }
}

// ---------------------------------------------------------------------------
// In-register P redistribution (verified passing in r1/r2).
// ---------------------------------------------------------------------------
__device__ __forceinline__ short8 build_pa(unsigned A0, unsigned A1,
                                           unsigned B0, unsigned B1, int quad) {
  int xA0 = __shfl_xor((int)A0, 32);
  int xA1 = __shfl_xor((int)A1, 32);
  int xB0 = __shfl_xor((int)B0, 32);
  int xB1 = __shfl_xor((int)B1, 32);
  const bool hi = quad >= 2;
  const bool odd = quad & 1;
  int Lo0 = hi ? xB0 : (int)A0;   // [A_lo | B_lo]
  int Lo1 = hi ? xB1 : (int)A1;
  int Hi0 = hi ? (int)B0 : xA0;   // [A_hi | B_hi]
  int Hi1 = hi ? (int)B1 : xA1;
  int xLo0 = __shfl_xor(Lo0, 16);
  int xLo1 = __shfl_xor(Lo1, 16);
  int xHi0 = __shfl_xor(Hi0, 16);
  int xHi1 = __shfl_xor(Hi1, 16);
  int4 wv;
  wv.x = odd ? xHi0 : Lo0;   // keys quad*8 + 0,1
  wv.y = odd ? xHi1 : Lo1;   // keys quad*8 + 2,3
  wv.z = odd ? Hi0 : xLo0;   // keys quad*8 + 4,5
  wv.w = odd ? Hi1 : xLo1;   // keys quad*8 + 6,7
  return *(short8*)&wv;
}

// exp + in-register P build + PV for one 16-query half. MASKED compile-time.
template<bool MASKED>
__device__ __forceinline__ void attn_half(
    const f32x4 (&c)[4], float& l_acc, f32x4 (&acc)[4],
    const short8 (&vf0)[4], const short8 (&vf1)[4],
    int keybase, int qabs, int quad)
{
  unsigned pk[4][2];
#pragma unroll
  for (int ct = 0; ct < 4; ++ct) {
    float pe[4];
#pragma unroll
    for (int r = 0; r < 4; ++r) {
      float p = __builtin_amdgcn_exp2f(c[ct][r] * SCL2E);
      if (MASKED && (keybase + ct * 16 + quad * 4 + r > qabs)) p = 0.f;
      pe[r] = p;
      l_acc += p;
    }
    pk[ct][0] = cvtpk_bf16(pe[0], pe[1]);
    pk[ct][1] = cvtpk_bf16(pe[2], pe[3]);
  }
  short8 pa0 = build_pa(pk[0][0], pk[0][1], pk[1][0], pk[1][1], quad);
  short8 pa1 = build_pa(pk[2][0], pk[2][1], pk[3][0], pk[3][1], quad);
  __builtin_amdgcn_s_setprio(1);
#pragma unroll
  for (int nt = 0; nt < 4; ++nt) {
    acc[nt] = __builtin_amdgcn_mfma_f32_16x16x32_bf16(pa0, vf0[nt], acc[nt], 0, 0, 0);
    acc[nt] = __builtin_amdgcn_mfma_f32_16x16x32_bf16(pa1, vf1[nt], acc[nt], 0, 0, 0);
  }
  __builtin_amdgcn_s_setprio(0);
}

// ---------------------------------------------------------------------------
// Flash causal attention v4: r1 structure (32q/block, 4-wave key-split,
// in-register softmax) + small-LDS two-buffer combine + launch_bounds(256,4)
// (VGPR cap 128 -> NO spill; r2's (256,6) forced VGPR 40 and spilled the
// fragment set to scratch: 253 MB writes / 105 MB fetch, 113 us).
// LDS 17.9 KB -> whole 1024-block grid co-resident at 4 blocks/CU.
// ---------------------------------------------------------------------------
__global__ __launch_bounds__(256, 4) void attn_kernel(
    const ushort* __restrict__ qg, const ushort* __restrict__ kg,
    const ushort* __restrict__ vT, float* __restrict__ out)
{
  __shared__ __align__(16) float accW[2][32][68];   // 17408 B
  __shared__ float lW[4][32];

  const int t = threadIdx.x, bid = blockIdx.x;
  const int batch = (bid & 7) * 2 + ((bid >> 3) & 1);  // 2 batches per XCD
  const int qt = 63 - (bid >> 4);                      // heavy blocks first
  const int q0 = qt * 32;
  const int lane = t & 63, w = t >> 6;
  const int l15 = lane & 15, quad = lane >> 4;
  const size_t bbase = (size_t)batch * SS * DD;

  // Q fragments (B operand of swapped QK): lane l15 = query row
  const ushort* qp = qg + bbase + (size_t)(q0 + l15) * 64 + quad * 8;
  short8 a0 = *(const short8*)qp;
  short8 a1 = *(const short8*)(qp + 32);
  short8 a2 = *(const short8*)(qp + 16 * 64);
  short8 a3 = *(const short8*)(qp + 16 * 64 + 32);

  f32x4 acc0[4], acc1[4];
  float l0 = 0.f, l1 = 0.f;
#pragma unroll
  for (int nt = 0; nt < 4; ++nt) {
    acc0[nt] = (f32x4){0.f, 0.f, 0.f, 0.f};
    acc1[nt] = (f32x4){0.f, 0.f, 0.f, 0.f};
  }

  const int ktotal = ((q0 + 31) >> 6) + 1;   // 64-key tiles
  const ushort* kp0 = kg + bbase + (size_t)(w * 64 + l15) * 64 + quad * 8;
  const ushort* kp1 = kp0 + 2048;            // +32 key rows
  const ushort* vp0 = vT + bbase + (size_t)(l15) * SS + w * 64 + quad * 8;
  const ushort* vp1 = vp0 + 16 * SS;
  const ushort* vp2 = vp0 + 32 * SS;
  const ushort* vp3 = vp0 + 48 * SS;

  const int qabs0 = q0 + l15, qabs1 = q0 + 16 + l15;

  for (int kt = w; kt < ktotal; kt += 4) {
    short8 kf0[4], kf1[4], vf0[4], vf1[4];
    kf0[0] = *(const short8*)(kp0);
    kf1[0] = *(const short8*)(kp0 + 32);
    kf0[1] = *(const short8*)(kp0 + 1024);
    kf1[1] = *(const short8*)(kp0 + 1056);
    kf0[2] = *(const short8*)(kp1);
    kf1[2] = *(const short8*)(kp1 + 32);
    kf0[3] = *(const short8*)(kp1 + 1024);
    kf1[3] = *(const short8*)(kp1 + 1056);
    vf0[0] = *(const short8*)(vp0); vf1[0] = *(const short8*)(vp0 + 32);
    vf0[1] = *(const short8*)(vp1); vf1[1] = *(const short8*)(vp1 + 32);
    vf0[2] = *(const short8*)(vp2); vf1[2] = *(const short8*)(vp2 + 32);
    vf0[3] = *(const short8*)(vp3); vf1[3] = *(const short8*)(vp3 + 32);

    // Swapped QK: c = mfma(K, Q) -> S^T tile; lane l15 = query.
    f32x4 c0[4], c1[4];
    __builtin_amdgcn_s_setprio(1);
#pragma unroll
    for (int ct = 0; ct < 4; ++ct) {
      f32x4 z = {0.f, 0.f, 0.f, 0.f};
      c0[ct] = __builtin_amdgcn_mfma_f32_16x16x32_bf16(kf0[ct], a0, z, 0, 0, 0);
      c0[ct] = __builtin_amdgcn_mfma_f32_16x16x32_bf16(kf1[ct], a1, c0[ct], 0, 0, 0);
      c1[ct] = __builtin_amdgcn_mfma_f32_16x16x32_bf16(kf0[ct], a2, z, 0, 0, 0);
      c1[ct] = __builtin_amdgcn_mfma_f32_16x16x32_bf16(kf1[ct], a3, c1[ct], 0, 0, 0);
    }
    __builtin_amdgcn_s_setprio(0);

    const int kb = kt * 64;
    if (kt == ktotal - 1) {
      attn_half<true >(c0, l0, acc0, vf0, vf1, kb, qabs0, quad);
      attn_half<true >(c1, l1, acc1, vf0, vf1, kb, qabs1, quad);
    } else {
      attn_half<false>(c0, l0, acc0, vf0, vf1, kb, qabs0, quad);
      attn_half<false>(c1, l1, acc1, vf0, vf1, kb, qabs1, quad);
    }
    kp0 += 16384; kp1 += 16384;
    vp0 += 256; vp1 += 256; vp2 += 256; vp3 += 256;
  }

  // l is per-lane (q = l15); sum across the 4 quads holding different keys
  l0 += __shfl_xor(l0, 16); l0 += __shfl_xor(l0, 32);
  l1 += __shfl_xor(l1, 16); l1 += __shfl_xor(l1, 32);

  // two-buffer combine: waves 0/1 write, waves 2/3 add (disjoint buffers)
  if (lane < 16) {
    lW[w][lane] = l0;
    lW[w][16 + lane] = l1;
  }
  if (w < 2) {
#pragma unroll
    for (int r = 0; r < 4; ++r)
#pragma unroll
      for (int nt = 0; nt < 4; ++nt) {
        accW[w][quad * 4 + r][nt * 16 + l15] = acc0[nt][r];
        accW[w][16 + quad * 4 + r][nt * 16 + l15] = acc1[nt][r];
      }
  }
  __syncthreads();
  if (w >= 2) {
#pragma unroll
    for (int r = 0; r < 4; ++r)
#pragma unroll
      for (int nt = 0; nt < 4; ++nt) {
        accW[w - 2][quad * 4 + r][nt * 16 + l15] += acc0[nt][r];
        accW[w - 2][16 + quad * 4 + r][nt * 16 + l15] += acc1[nt][r];
      }
  }
  __syncthreads();

  // combine: plain sums, 8 floats per thread, coalesced
  {
    const int row = t >> 3, col0 = (t & 7) * 8;
    float den = lW[0][row] + lW[1][row] + lW[2][row] + lW[3][row];
    float iv = 1.0f / den;
    float4 oa, ob;
    {
      float4 x0 = *(const float4*)&accW[0][row][col0];
      float4 x1 = *(const float4*)&accW[0][row][col0 + 4];
      float4 y0 = *(const float4*)&accW[1][row][col0];
      float4 y1 = *(const float4*)&accW[1][row][col0 + 4];
      oa.x = x0.x + y0.x; oa.y = x0.y + y0.y; oa.z = x0.z + y0.z; oa.w = x0.w + y0.w;
      ob.x = x1.x + y1.x; ob.y = x1.y + y1.y; ob.z = x1.z + y1.z; ob.w = x1.w + y1.w;
    }
    oa.x *= iv; oa.y *= iv; oa.z *= iv; oa.w *= iv;
    ob.x *= iv; ob.y *= iv; ob.z *= iv; ob.w *= iv;
    float* op = out + bbase + (size_t)(q0 + row) * 64 + col0;
    *(float4*)op = oa;
    *(float4*)(op + 4) = ob;
  }
}

extern "C" void kernel_launch(void* const* d_in, const int* in_sizes, int n_in,
                              void* d_out, int out_size, void* d_ws, size_t ws_size,
                              hipStream_t stream) {
  (void)in_sizes; (void)n_in; (void)out_size; (void)ws_size;
  const float* x  = (const float*)d_in[0];
  const float* Wq = (const float*)d_in[1];
  const float* bq = (const float*)d_in[2];
  const float* Wk = (const float*)d_in[3];
  const float* bk = (const float*)d_in[4];
  const float* Wv = (const float*)d_in[5];
  const float* bv = (const float*)d_in[6];
  float* out = (float*)d_out;

  ushort* qws = (ushort*)d_ws;                       // bf16 q: 4 MB
  ushort* kws = qws + (size_t)NB * SS * DD;          // bf16 k: 4 MB
  ushort* vws = kws + (size_t)NB * SS * DD;          // bf16 v^T: 4 MB

  proj_kernel<<<dim3(NB * SS / 64), dim3(256), 0, stream>>>(
      x, Wq, bq, Wk, bk, Wv, bv, qws, kws, vws);
  attn_kernel<<<dim3(NB * (SS / 32)), dim3(256), 0, stream>>>(
      qws, kws, vws, out);
}

// Round 4
// 118.862 us; speedup vs baseline: 1.6135x; 1.0623x over previous
//
#include <hip/hip_runtime.h>

#define NB 16
#define SS 2048
#define DD 64

typedef __attribute__((ext_vector_type(8))) short short8;
typedef __attribute__((ext_vector_type(4))) float f32x4;

// SCALE * log2(e), folded so softmax exp is one v_mul + one v_exp
#define SCL2E 0.18033688011112042f

// round-to-nearest-even f32 -> bf16 (as raw short)
__device__ __forceinline__ short f2bf(float f) {
  union { float f; unsigned u; } v; v.f = f;
  unsigned r = (v.u + 0x7fffu + ((v.u >> 16) & 1u)) >> 16;
  return (short)r;
}

// packed RNE f32x2 -> bf16x2 (no builtin on gfx950; guide T12)
__device__ __forceinline__ unsigned cvtpk_bf16(float lo, float hi) {
  unsigned r;
  asm("v_cvt_pk_bf16_f32 %0, %1, %2" : "=v"(r) : "v"(lo), "v"(hi));
  return r;
}

__device__ __forceinline__ short8 load_a_frag_f32(const float* p) {
  float4 u = *(const float4*)p;
  float4 w = *(const float4*)(p + 4);
  short8 r;
  r[0] = f2bf(u.x); r[1] = f2bf(u.y); r[2] = f2bf(u.z); r[3] = f2bf(u.w);
  r[4] = f2bf(w.x); r[5] = f2bf(w.y); r[6] = f2bf(w.z); r[7] = f2bf(w.w);
  return r;
}

// ---------------------------------------------------------------------------
// QKV projection v5: 768 threads (12 waves), 512 blocks, 64 rows/block.
// Staging spread over 3x threads (4 float4 / 16 cvt / 16 ds_write per thread);
// wave w owns matrix m = w>>2 and rows (w&3)*16 -> 6144 waves (3x r0).
// Swapped MFMA orientation (A = W^T from LDS, B = x rows) -> lane holds 4
// consecutive output cols -> one packed 8B store per nt (16x fewer store
// instrs than r0's scalar ushort stores). Orientation HW-verified in r1.
// ---------------------------------------------------------------------------
__global__ __launch_bounds__(768) void proj_kernel(
    const float* __restrict__ x,
    const float* __restrict__ Wq, const float* __restrict__ bq,
    const float* __restrict__ Wk, const float* __restrict__ bk,
    const float* __restrict__ Wv, const float* __restrict__ bv,
    ushort* __restrict__ qo, ushort* __restrict__ ko, ushort* __restrict__ vT)
{
  __shared__ __align__(16) ushort Wt[3][64][72];   // W^T[n][k], bf16
  __shared__ __align__(16) ushort Vs[64][68];
  const int t = threadIdx.x;
  // stage all three W^T: 12288 elems over 768 threads (4 elems x 4 iters)
#pragma unroll
  for (int i = 0; i < 4; ++i) {
    int idx = i * 3072 + t * 4;
    int m = idx >> 12, rem = idx & 4095;
    int kk = rem >> 6, n0 = rem & 63;
    const float* src = (m == 0 ? Wq : (m == 1 ? Wk : Wv));
    float4 w4 = *(const float4*)(src + rem);
    Wt[m][n0 + 0][kk] = (ushort)f2bf(w4.x);
    Wt[m][n0 + 1][kk] = (ushort)f2bf(w4.y);
    Wt[m][n0 + 2][kk] = (ushort)f2bf(w4.z);
    Wt[m][n0 + 3][kk] = (ushort)f2bf(w4.w);
  }
  __syncthreads();

  const int lane = t & 63, w = t >> 6;   // w in 0..11
  const int l15 = lane & 15, quad = lane >> 4;
  const int mm = w >> 2, rr = w & 3;     // matrix, row-quarter
  const int g = blockIdx.x * 64 + rr * 16 + l15;

  // B-frags: x row g (waves with same rr share rows; L1 hits)
  short8 b0 = load_a_frag_f32(x + (size_t)g * 64 + quad * 8);
  short8 b1 = load_a_frag_f32(x + (size_t)g * 64 + 32 + quad * 8);

  const float* bp = (mm == 0 ? bq : (mm == 1 ? bk : bv));
  ushort* outp = (mm == 0 ? qo : ko);

#pragma unroll
  for (int nt = 0; nt < 4; ++nt) {
    short8 a0 = *(const short8*)&Wt[mm][nt * 16 + l15][quad * 8];
    short8 a1 = *(const short8*)&Wt[mm][nt * 16 + l15][32 + quad * 8];
    f32x4 acc = {0.f, 0.f, 0.f, 0.f};
    acc = __builtin_amdgcn_mfma_f32_16x16x32_bf16(a0, b0, acc, 0, 0, 0);
    acc = __builtin_amdgcn_mfma_f32_16x16x32_bf16(a1, b1, acc, 0, 0, 0);
    float4 bb = *(const float4*)(bp + nt * 16 + quad * 4);
    uint2 pk;
    pk.x = cvtpk_bf16(acc[0] + bb.x, acc[1] + bb.y);
    pk.y = cvtpk_bf16(acc[2] + bb.z, acc[3] + bb.w);
    if (mm == 2) {
      *(uint2*)&Vs[rr * 16 + l15][nt * 16 + quad * 4] = pk;
    } else {
      *(uint2*)(outp + (size_t)g * 64 + nt * 16 + quad * 4) = pk;
    }
  }
  __syncthreads();
  if (t < 256) {
    const int batch = blockIdx.x >> 5;
    const int s0 = (blockIdx.x & 31) * 64;
    const int d = t >> 2, j0 = (t & 3) * 16;
    ushort tmp[16];
#pragma unroll
    for (int j = 0; j < 16; ++j) tmp[j] = Vs[j0 + j][d];
    ushort* dst = vT + (size_t)batch * DD * SS + (size_t)d * SS + s0 + j0;
    ((int4*)dst)[0] = ((int4*)tmp)[0];
    ((int4*)dst)[1] = ((int4*)tmp)[1];
  }
}

// ---------------------------------------------------------------------------
// In-register P redistribution (verified passing r1/r2/r3).
// ---------------------------------------------------------------------------
__device__ __forceinline__ short8 build_pa(unsigned A0, unsigned A1,
                                           unsigned B0, unsigned B1, int quad) {
  int xA0 = __shfl_xor((int)A0, 32);
  int xA1 = __shfl_xor((int)A1, 32);
  int xB0 = __shfl_xor((int)B0, 32);
  int xB1 = __shfl_xor((int)B1, 32);
  const bool hi = quad >= 2;
  const bool odd = quad & 1;
  int Lo0 = hi ? xB0 : (int)A0;   // [A_lo | B_lo]
  int Lo1 = hi ? xB1 : (int)A1;
  int Hi0 = hi ? (int)B0 : xA0;   // [A_hi | B_hi]
  int Hi1 = hi ? (int)B1 : xA1;
  int xLo0 = __shfl_xor(Lo0, 16);
  int xLo1 = __shfl_xor(Lo1, 16);
  int xHi0 = __shfl_xor(Hi0, 16);
  int xHi1 = __shfl_xor(Hi1, 16);
  int4 wv;
  wv.x = odd ? xHi0 : Lo0;   // keys quad*8 + 0,1
  wv.y = odd ? xHi1 : Lo1;   // keys quad*8 + 2,3
  wv.z = odd ? Hi0 : xLo0;   // keys quad*8 + 4,5
  wv.w = odd ? Hi1 : xLo1;   // keys quad*8 + 6,7
  return *(short8*)&wv;
}

// exp + in-register P build + PV for one 16-query half. MASKED compile-time.
template<bool MASKED>
__device__ __forceinline__ void attn_half(
    const f32x4 (&c)[4], float& l_acc, f32x4 (&acc)[4],
    const short8 (&vf0)[4], const short8 (&vf1)[4],
    int keybase, int qabs, int quad)
{
  unsigned pk[4][2];
#pragma unroll
  for (int ct = 0; ct < 4; ++ct) {
    float pe[4];
#pragma unroll
    for (int r = 0; r < 4; ++r) {
      float p = __builtin_amdgcn_exp2f(c[ct][r] * SCL2E);
      if (MASKED && (keybase + ct * 16 + quad * 4 + r > qabs)) p = 0.f;
      pe[r] = p;
      l_acc += p;
    }
    pk[ct][0] = cvtpk_bf16(pe[0], pe[1]);
    pk[ct][1] = cvtpk_bf16(pe[2], pe[3]);
  }
  short8 pa0 = build_pa(pk[0][0], pk[0][1], pk[1][0], pk[1][1], quad);
  short8 pa1 = build_pa(pk[2][0], pk[2][1], pk[3][0], pk[3][1], quad);
  __builtin_amdgcn_s_setprio(1);
#pragma unroll
  for (int nt = 0; nt < 4; ++nt) {
    acc[nt] = __builtin_amdgcn_mfma_f32_16x16x32_bf16(pa0, vf0[nt], acc[nt], 0, 0, 0);
    acc[nt] = __builtin_amdgcn_mfma_f32_16x16x32_bf16(pa1, vf1[nt], acc[nt], 0, 0, 0);
  }
  __builtin_amdgcn_s_setprio(0);
}

// K fragments for one 64-key tile (8 x short8 = 32 VGPR). Constant-indexed.
struct KFrag { short8 f0[4]; short8 f1[4]; };

__device__ __forceinline__ void load_k(KFrag& K, const ushort* kp0,
                                       const ushort* kp1) {
  K.f0[0] = *(const short8*)(kp0);
  K.f1[0] = *(const short8*)(kp0 + 32);
  K.f0[1] = *(const short8*)(kp0 + 1024);
  K.f1[1] = *(const short8*)(kp0 + 1056);
  K.f0[2] = *(const short8*)(kp1);
  K.f1[2] = *(const short8*)(kp1 + 32);
  K.f0[3] = *(const short8*)(kp1 + 1024);
  K.f1[3] = *(const short8*)(kp1 + 1056);
}

// One key-tile: issue V loads first (consumed ~450 cyc later, after QK +
// softmax), then QK MFMAs on the PREFETCHED K, then softmax + PV.
template<bool MASKED>
__device__ __forceinline__ void tile_compute(
    const KFrag& K,
    const ushort* vp0, const ushort* vp1, const ushort* vp2, const ushort* vp3,
    const short8& a0, const short8& a1, const short8& a2, const short8& a3,
    f32x4 (&acc0)[4], f32x4 (&acc1)[4], float& l0, float& l1,
    int kb, int qabs0, int qabs1, int quad)
{
  short8 vf0[4], vf1[4];
  vf0[0] = *(const short8*)(vp0); vf1[0] = *(const short8*)(vp0 + 32);
  vf0[1] = *(const short8*)(vp1); vf1[1] = *(const short8*)(vp1 + 32);
  vf0[2] = *(const short8*)(vp2); vf1[2] = *(const short8*)(vp2 + 32);
  vf0[3] = *(const short8*)(vp3); vf1[3] = *(const short8*)(vp3 + 32);

  f32x4 c0[4], c1[4];
  __builtin_amdgcn_s_setprio(1);
#pragma unroll
  for (int ct = 0; ct < 4; ++ct) {
    f32x4 z = {0.f, 0.f, 0.f, 0.f};
    c0[ct] = __builtin_amdgcn_mfma_f32_16x16x32_bf16(K.f0[ct], a0, z, 0, 0, 0);
    c0[ct] = __builtin_amdgcn_mfma_f32_16x16x32_bf16(K.f1[ct], a1, c0[ct], 0, 0, 0);
    c1[ct] = __builtin_amdgcn_mfma_f32_16x16x32_bf16(K.f0[ct], a2, z, 0, 0, 0);
    c1[ct] = __builtin_amdgcn_mfma_f32_16x16x32_bf16(K.f1[ct], a3, c1[ct], 0, 0, 0);
  }
  __builtin_amdgcn_s_setprio(0);

  attn_half<MASKED>(c0, l0, acc0, vf0, vf1, kb, qabs0, quad);
  attn_half<MASKED>(c1, l1, acc1, vf0, vf1, kb, qabs1, quad);
}

// ---------------------------------------------------------------------------
// Flash causal attention v6: r1 structure (32q/block, 4-wave key-split,
// in-register softmax) + explicit K double-buffer (KA/KB, 2-phase unroll,
// constant indexing only) so QK never stalls on K-load latency.
// launch_bounds(256,2): VGPR cap 256 -> allocator has room for the pipeline
// (r2/r3 proved squeezing VGPR to 40/64 costs 2.8x/1.25x via scratch).
// ---------------------------------------------------------------------------
__global__ __launch_bounds__(256, 2) void attn_kernel(
    const ushort* __restrict__ qg, const ushort* __restrict__ kg,
    const ushort* __restrict__ vT, float* __restrict__ out)
{
  __shared__ __align__(16) float accW[2][32][68];   // 17408 B
  __shared__ float lW[4][32];

  const int t = threadIdx.x, bid = blockIdx.x;
  const int batch = (bid & 7) * 2 + ((bid >> 3) & 1);  // 2 batches per XCD
  const int qt = 63 - (bid >> 4);                      // heavy blocks first
  const int q0 = qt * 32;
  const int lane = t & 63, w = t >> 6;
  const int l15 = lane & 15, quad = lane >> 4;
  const size_t bbase = (size_t)batch * SS * DD;

  // Q fragments (B operand of swapped QK): lane l15 = query row
  const ushort* qp = qg + bbase + (size_t)(q0 + l15) * 64 + quad * 8;
  short8 a0 = *(const short8*)qp;
  short8 a1 = *(const short8*)(qp + 32);
  short8 a2 = *(const short8*)(qp + 16 * 64);
  short8 a3 = *(const short8*)(qp + 16 * 64 + 32);

  f32x4 acc0[4], acc1[4];
  float l0 = 0.f, l1 = 0.f;
#pragma unroll
  for (int nt = 0; nt < 4; ++nt) {
    acc0[nt] = (f32x4){0.f, 0.f, 0.f, 0.f};
    acc1[nt] = (f32x4){0.f, 0.f, 0.f, 0.f};
  }

  const int ktotal = ((q0 + 31) >> 6) + 1;   // 64-key tiles
  const ushort* kp0 = kg + bbase + (size_t)(w * 64 + l15) * 64 + quad * 8;
  const ushort* kp1 = kp0 + 2048;            // +32 key rows
  const ushort* vp0 = vT + bbase + (size_t)(l15) * SS + w * 64 + quad * 8;
  const ushort* vp1 = vp0 + 16 * SS;
  const ushort* vp2 = vp0 + 32 * SS;
  const ushort* vp3 = vp0 + 48 * SS;

  const int qabs0 = q0 + l15, qabs1 = q0 + 16 + l15;

  int kt = w;
  if (kt < ktotal) {
    KFrag KA, KB;
    load_k(KA, kp0, kp1);
    kp0 += 16384; kp1 += 16384;
    while (true) {
      int ktn = kt + 4;
      if (ktn < ktotal) { load_k(KB, kp0, kp1); kp0 += 16384; kp1 += 16384; }
      if (kt == ktotal - 1)
        tile_compute<true >(KA, vp0, vp1, vp2, vp3, a0, a1, a2, a3,
                            acc0, acc1, l0, l1, kt * 64, qabs0, qabs1, quad);
      else
        tile_compute<false>(KA, vp0, vp1, vp2, vp3, a0, a1, a2, a3,
                            acc0, acc1, l0, l1, kt * 64, qabs0, qabs1, quad);
      vp0 += 256; vp1 += 256; vp2 += 256; vp3 += 256;
      if (ktn >= ktotal) break;
      kt = ktn;
      ktn = kt + 4;
      if (ktn < ktotal) { load_k(KA, kp0, kp1); kp0 += 16384; kp1 += 16384; }
      if (kt == ktotal - 1)
        tile_compute<true >(KB, vp0, vp1, vp2, vp3, a0, a1, a2, a3,
                            acc0, acc1, l0, l1, kt * 64, qabs0, qabs1, quad);
      else
        tile_compute<false>(KB, vp0, vp1, vp2, vp3, a0, a1, a2, a3,
                            acc0, acc1, l0, l1, kt * 64, qabs0, qabs1, quad);
      vp0 += 256; vp1 += 256; vp2 += 256; vp3 += 256;
      if (ktn >= ktotal) break;
      kt = ktn;
    }
  }

  // l is per-lane (q = l15); sum across the 4 quads holding different keys
  l0 += __shfl_xor(l0, 16); l0 += __shfl_xor(l0, 32);
  l1 += __shfl_xor(l1, 16); l1 += __shfl_xor(l1, 32);

  // two-buffer combine: waves 0/1 write, waves 2/3 add (disjoint buffers)
  if (lane < 16) {
    lW[w][lane] = l0;
    lW[w][16 + lane] = l1;
  }
  if (w < 2) {
#pragma unroll
    for (int r = 0; r < 4; ++r)
#pragma unroll
      for (int nt = 0; nt < 4; ++nt) {
        accW[w][quad * 4 + r][nt * 16 + l15] = acc0[nt][r];
        accW[w][16 + quad * 4 + r][nt * 16 + l15] = acc1[nt][r];
      }
  }
  __syncthreads();
  if (w >= 2) {
#pragma unroll
    for (int r = 0; r < 4; ++r)
#pragma unroll
      for (int nt = 0; nt < 4; ++nt) {
        accW[w - 2][quad * 4 + r][nt * 16 + l15] += acc0[nt][r];
        accW[w - 2][16 + quad * 4 + r][nt * 16 + l15] += acc1[nt][r];
      }
  }
  __syncthreads();

  // combine: plain sums, 8 floats per thread, coalesced
  {
    const int row = t >> 3, col0 = (t & 7) * 8;
    float den = lW[0][row] + lW[1][row] + lW[2][row] + lW[3][row];
    float iv = 1.0f / den;
    float4 oa, ob;
    {
      float4 x0 = *(const float4*)&accW[0][row][col0];
      float4 x1 = *(const float4*)&accW[0][row][col0 + 4];
      float4 y0 = *(const float4*)&accW[1][row][col0];
      float4 y1 = *(const float4*)&accW[1][row][col0 + 4];
      oa.x = x0.x + y0.x; oa.y = x0.y + y0.y; oa.z = x0.z + y0.z; oa.w = x0.w + y0.w;
      ob.x = x1.x + y1.x; ob.y = x1.y + y1.y; ob.z = x1.z + y1.z; ob.w = x1.w + y1.w;
    }
    oa.x *= iv; oa.y *= iv; oa.z *= iv; oa.w *= iv;
    ob.x *= iv; ob.y *= iv; ob.z *= iv; ob.w *= iv;
    float* op = out + bbase + (size_t)(q0 + row) * 64 + col0;
    *(float4*)op = oa;
    *(float4*)(op + 4) = ob;
  }
}

extern "C" void kernel_launch(void* const* d_in, const int* in_sizes, int n_in,
                              void* d_out, int out_size, void* d_ws, size_t ws_size,
                              hipStream_t stream) {
  (void)in_sizes; (void)n_in; (void)out_size; (void)ws_size;
  const float* x  = (const float*)d_in[0];
  const float* Wq = (const float*)d_in[1];
  const float* bq = (const float*)d_in[2];
  const float* Wk = (const float*)d_in[3];
  const float* bk = (const float*)d_in[4];
  const float* Wv = (const float*)d_in[5];
  const float* bv = (const float*)d_in[6];
  float* out = (float*)d_out;

  ushort* qws = (ushort*)d_ws;                       // bf16 q: 4 MB
  ushort* kws = qws + (size_t)NB * SS * DD;          // bf16 k: 4 MB
  ushort* vws = kws + (size_t)NB * SS * DD;          // bf16 v^T: 4 MB

  proj_kernel<<<dim3(NB * SS / 64), dim3(768), 0, stream>>>(
      x, Wq, bq, Wk, bk, Wv, bv, qws, kws, vws);
  attn_kernel<<<dim3(NB * (SS / 32)), dim3(256), 0, stream>>>(
      qws, kws, vws, out);
}